// Round 12
// baseline (781.663 us; speedup 1.0000x reference)
//
#include <hip/hip_runtime.h>

#define N_NODES 100000
#define N_EDGES 3200000
#define BATCH 16384
#define MAX_SLOTS 32768
#define MAGIC 0x5A5A5A5Au

#define GRID 512
#define TPB 512

// Degree histogram: nibble-packed, all 100K nodes in 50 KB LDS, 256 slices x 12500 edges.
#define NW 12500        // nibble words (8 nodes/word)
#define HSLICES 256
// Scatter: 512 sub-slices x 6250 edges (int2-aligned).
#define NSUB 512
#define NBUCK 256
#define BSH 7

// Workspace layout (byte offsets). ws_size = 256 MiB.
#define OFF_SLOT      0          // 100000 u32
#define OFF_COUNTERS  400000     // 16 ints: [0]=nSlots, [1]=grid barrier counter
#define OFF_DINV      400064     // 100000 f32
#define OFF_NODELIST  800064     // 32768 ints
#define OFF_BTOT      931136     // 256 ints
#define OFF_BPART     932160     // 256 x 512 ints [bucket][subslice]
#define OFF_SLOTSTART 1456448    // 32769 ints
#define OFF_PARTIALS  1587584    // 256 x 12500 words = 12.8 MB nibble degree counts
#define OFF_WH        14387584   // bf16 w*dinv, 100000x64x2 B
#define OFF_BINS      27187584   // packed (slot_local<<17|src), cap 1.2M
#define OFF_BINS2     31987584   // slot-sorted src ids, cap 1.2M
#define OFF_EMB       36787584   // bf16 32768x64

__device__ __forceinline__ unsigned bfr(float f) {   // fp32 -> bf16 bits, RNE
    unsigned u = __float_as_uint(f);
    return (u + 0x7FFFu + ((u >> 16) & 1u)) >> 16;
}
__device__ __forceinline__ float bfx(unsigned h) {   // low 16 bits -> fp32
    return __uint_as_float(h << 16);
}

// Software grid barrier. CRITICAL: poll with device-scope atomic LOAD (read-only,
// no cacheline ownership) — polling with atomicAdd(cnt,0) RMWs serialized all 512
// blocks at the coherence point and cost ~65 us/barrier (round-11 post-mortem).
__device__ __forceinline__ void gbar(int* cnt, int target) {
    __syncthreads();
    if (threadIdx.x == 0) {
        __threadfence();                      // make this block's writes visible
        __hip_atomic_fetch_add(cnt, 1, __ATOMIC_RELEASE, __HIP_MEMORY_SCOPE_AGENT);
        while (__hip_atomic_load(cnt, __ATOMIC_ACQUIRE, __HIP_MEMORY_SCOPE_AGENT) < target)
            __builtin_amdgcn_s_sleep(32);
        __threadfence();                      // order subsequent reads after observation
    }
    __syncthreads();
}

// Launch 1: zero counters (incl. barrier counter) + mark needed nodes with MAGIC.
__global__ void k_init0(const int* __restrict__ pairs, unsigned* __restrict__ slot,
                        int* __restrict__ counters) {
    int i = blockIdx.x * blockDim.x + threadIdx.x;
    if (i < 16) counters[i] = 0;
    if (i < 2 * BATCH) slot[pairs[i]] = MAGIC;
}

__global__ __launch_bounds__(TPB, 4) void k_mega(
        const float4* __restrict__ w4, const float4* __restrict__ bias4,
        const float* __restrict__ lw, const float* __restrict__ lb,
        const int* __restrict__ src, const int* __restrict__ dst,
        const int* __restrict__ pairs, float* __restrict__ out, char* __restrict__ ws) {
    unsigned* slot      = (unsigned*)(ws + OFF_SLOT);
    int*      counters  = (int*)     (ws + OFF_COUNTERS);
    float*    dinv      = (float*)   (ws + OFF_DINV);
    int*      nodelist  = (int*)     (ws + OFF_NODELIST);
    int*      btot      = (int*)     (ws + OFF_BTOT);
    int*      bpart     = (int*)     (ws + OFF_BPART);
    int*      slotstart = (int*)     (ws + OFF_SLOTSTART);
    unsigned* partials  = (unsigned*)(ws + OFF_PARTIALS);
    uint4*    wh4       = (uint4*)   (ws + OFF_WH);
    int*      bins      = (int*)     (ws + OFF_BINS);
    int*      bins2     = (int*)     (ws + OFF_BINS2);
    uint4*    emb4      = (uint4*)   (ws + OFF_EMB);
    const uint2* emb2   = (const uint2*)(ws + OFF_EMB);
    int* cnt = &counters[1];

    __shared__ union SM {
        struct { unsigned h[NW]; int lc[2][NBUCK]; } c;                 // 52048 B max
        struct { unsigned p[4][TPB]; float sdinv[256]; } d;
        struct { int t[NSUB]; } pfx;
        struct { int tb[NBUCK], vv[NBUCK], cur[NBUCK]; } e;
        struct { int tb[NBUCK], vv[NBUCK], lc[128], st[128]; } f;
    } sm;

    int tid = threadIdx.x;

    // ---- Phase B: wave-aggregated compaction (writes every slot) ----
    {
        int n = blockIdx.x * TPB + tid;
        int lane = tid & 63;
        int want = (n < N_NODES && slot[n] == MAGIC) ? 1 : 0;
        int incl = want;
#pragma unroll
        for (int d = 1; d < 64; d <<= 1) {
            int t = __shfl_up(incl, d, 64);
            if (lane >= d) incl += t;
        }
        int total = __shfl(incl, 63, 64);
        int base = 0;
        if (lane == 63 && total > 0) base = atomicAdd(&counters[0], total);
        base = __shfl(base, 63, 64);
        if (n < N_NODES) {
            if (want) {
                int s = base + incl - 1;
                slot[n] = (unsigned)(s + 1);
                nodelist[s] = n;
            } else {
                slot[n] = 0u;
            }
        }
    }
    gbar(cnt, GRID);

    // ---- Phase C: nibble degree hist (all nodes) + per-half-slice bucket counts ----
    if (blockIdx.x < HSLICES) {
        int g = blockIdx.x;
        for (int i = tid; i < NW; i += TPB) sm.c.h[i] = 0;
        if (tid < NBUCK) { sm.c.lc[0][tid] = 0; sm.c.lc[1][tid] = 0; }
        __syncthreads();
        const int4* d4 = (const int4*)(dst + g * 12500);
        for (int i = tid; i < 3125; i += TPB) {
            int4 v = d4[i];
            atomicAdd(&sm.c.h[v.x >> 3], 1u << ((v.x & 7) << 2));
            atomicAdd(&sm.c.h[v.y >> 3], 1u << ((v.y & 7) << 2));
            atomicAdd(&sm.c.h[v.z >> 3], 1u << ((v.z & 7) << 2));
            atomicAdd(&sm.c.h[v.w >> 3], 1u << ((v.w & 7) << 2));
            int s01 = (i * 4) >= 6250;
            int s23 = (i * 4 + 2) >= 6250;
            unsigned r;
            r = slot[v.x]; if (r) atomicAdd(&sm.c.lc[s01][(r - 1) >> BSH], 1);
            r = slot[v.y]; if (r) atomicAdd(&sm.c.lc[s01][(r - 1) >> BSH], 1);
            r = slot[v.z]; if (r) atomicAdd(&sm.c.lc[s23][(r - 1) >> BSH], 1);
            r = slot[v.w]; if (r) atomicAdd(&sm.c.lc[s23][(r - 1) >> BSH], 1);
        }
        __syncthreads();
        unsigned* outp = partials + (unsigned)g * NW;
        for (int i = tid; i < NW; i += TPB) outp[i] = sm.c.h[i];
        if (tid < NBUCK) {
            bpart[tid * NSUB + g * 2]     = sm.c.lc[0][tid];
            bpart[tid * NSUB + g * 2 + 1] = sm.c.lc[1][tid];
        }
    }
    gbar(cnt, 2 * GRID);

    // ---- Phase D: blocks <391: partials -> dinv + bf16 wh; blocks >=391: bucket row scans ----
    if (blockIdx.x < 391) {
        int wi = tid & 31, sg = tid >> 5;             // word-in-block, slice-group (16 groups x 16)
        int w = blockIdx.x * 32 + wi;
        unsigned A = 0, Bu = 0, Cu = 0, Du = 0;
        if (w < NW) {
            const unsigned* q = partials + w;
            unsigned x = 0, y = 0;
#pragma unroll
            for (int k = 0; k < 16; ++k) {
                unsigned v = q[(unsigned)(sg * 16 + k) * NW];
                x += v & 0x0F0F0F0Fu;
                y += (v >> 4) & 0x0F0F0F0Fu;
            }
            A = x & 0x00FF00FFu; Bu = (x >> 8) & 0x00FF00FFu;
            Cu = y & 0x00FF00FFu; Du = (y >> 8) & 0x00FF00FFu;
        }
        sm.d.p[0][tid] = A; sm.d.p[1][tid] = Bu; sm.d.p[2][tid] = Cu; sm.d.p[3][tid] = Du;
        __syncthreads();
        if (tid < 32 && w < NW) {
            unsigned sA = 0, sB = 0, sC = 0, sD = 0;
#pragma unroll
            for (int k = 0; k < 16; ++k) {
                sA += sm.d.p[0][k * 32 + tid]; sB += sm.d.p[1][k * 32 + tid];
                sC += sm.d.p[2][k * 32 + tid]; sD += sm.d.p[3][k * 32 + tid];
            }
            float4 d0, d1;
            d0.x = rsqrtf((float)(sA & 0xFFFFu) + 1.0f);
            d0.y = rsqrtf((float)(sC & 0xFFFFu) + 1.0f);
            d0.z = rsqrtf((float)(sB & 0xFFFFu) + 1.0f);
            d0.w = rsqrtf((float)(sD & 0xFFFFu) + 1.0f);
            d1.x = rsqrtf((float)(sA >> 16) + 1.0f);
            d1.y = rsqrtf((float)(sC >> 16) + 1.0f);
            d1.z = rsqrtf((float)(sB >> 16) + 1.0f);
            d1.w = rsqrtf((float)(sD >> 16) + 1.0f);
            ((float4*)dinv)[w * 2] = d0;
            ((float4*)dinv)[w * 2 + 1] = d1;
            int lbm = tid * 8;
            sm.d.sdinv[lbm + 0] = d0.x; sm.d.sdinv[lbm + 1] = d0.y;
            sm.d.sdinv[lbm + 2] = d0.z; sm.d.sdinv[lbm + 3] = d0.w;
            sm.d.sdinv[lbm + 4] = d1.x; sm.d.sdinv[lbm + 5] = d1.y;
            sm.d.sdinv[lbm + 6] = d1.z; sm.d.sdinv[lbm + 7] = d1.w;
        }
        __syncthreads();
#pragma unroll
        for (int it = 0; it < 4; ++it) {
            int k = blockIdx.x * 2048 + it * TPB + tid;   // uint4 idx (8 dims); node = k>>3
            if (k < N_NODES * 8) {
                float4 va = w4[k * 2];
                float4 vb = w4[k * 2 + 1];
                float d = sm.d.sdinv[(k >> 3) - blockIdx.x * 256];
                uint4 o;
                o.x = bfr(va.x * d) | (bfr(va.y * d) << 16);
                o.y = bfr(va.z * d) | (bfr(va.w * d) << 16);
                o.z = bfr(vb.x * d) | (bfr(vb.y * d) << 16);
                o.w = bfr(vb.z * d) | (bfr(vb.w * d) << 16);
                wh4[k] = o;
            }
        }
    } else {
        for (int r = blockIdx.x - 391; r < NBUCK; r += 121) {
            int v = bpart[r * NSUB + tid];
            sm.pfx.t[tid] = v;
            __syncthreads();
            for (int off = 1; off < NSUB; off <<= 1) {
                int x = (tid >= off) ? sm.pfx.t[tid - off] : 0;
                __syncthreads();
                sm.pfx.t[tid] += x;
                __syncthreads();
            }
            bpart[r * NSUB + tid] = sm.pfx.t[tid] - v;
            if (tid == NSUB - 1) btot[r] = sm.pfx.t[tid];
            __syncthreads();
        }
    }
    gbar(cnt, 3 * GRID);

    // ---- Phase E: deterministic scatter (512 sub-slices of 6250 edges, int2) ----
    {
        int u = blockIdx.x;
        if (tid < NBUCK) { int v = btot[tid]; sm.e.vv[tid] = v; sm.e.tb[tid] = v; }
        __syncthreads();
        for (int off = 1; off < NBUCK; off <<= 1) {
            int x = (tid < NBUCK && tid >= off) ? sm.e.tb[tid - off] : 0;
            __syncthreads();
            if (tid < NBUCK) sm.e.tb[tid] += x;
            __syncthreads();
        }
        if (tid < NBUCK) sm.e.cur[tid] = sm.e.tb[tid] - sm.e.vv[tid] + bpart[tid * NSUB + u];
        __syncthreads();
        const int2* d2 = (const int2*)(dst + u * 6250);
        const int2* s2 = (const int2*)(src + u * 6250);
        for (int i = tid; i < 3125; i += TPB) {
            int2 d = d2[i];
            int2 s = s2[i];
            unsigned r;
            r = slot[d.x];
            if (r) {
                int sl = (int)r - 1;
                int pos = atomicAdd(&sm.e.cur[sl >> BSH], 1);
                bins[pos] = ((sl & 127) << 17) | s.x;
            }
            r = slot[d.y];
            if (r) {
                int sl = (int)r - 1;
                int pos = atomicAdd(&sm.e.cur[sl >> BSH], 1);
                bins[pos] = ((sl & 127) << 17) | s.y;
            }
        }
    }
    gbar(cnt, 4 * GRID);

    // ---- Phase F: per-bucket counting sort -> per-slot CSR ----
    if (blockIdx.x < NBUCK) {
        int b = blockIdx.x;
        if (tid < NBUCK) { int v = btot[tid]; sm.f.vv[tid] = v; sm.f.tb[tid] = v; }
        __syncthreads();
        for (int off = 1; off < NBUCK; off <<= 1) {
            int x = (tid < NBUCK && tid >= off) ? sm.f.tb[tid - off] : 0;
            __syncthreads();
            if (tid < NBUCK) sm.f.tb[tid] += x;
            __syncthreads();
        }
        int beg = sm.f.tb[b] - sm.f.vv[b];
        int end = beg + sm.f.vv[b];
        if (tid < 128) sm.f.lc[tid] = 0;
        __syncthreads();
        for (int j = beg + tid; j < end; j += TPB)
            atomicAdd(&sm.f.lc[(bins[j] >> 17) & 127], 1);
        __syncthreads();
        if (tid < 128) sm.f.st[tid] = sm.f.lc[tid];
        __syncthreads();
        for (int off = 1; off < 128; off <<= 1) {
            int v = (tid < 128 && tid >= off) ? sm.f.st[tid - off] : 0;
            __syncthreads();
            if (tid < 128) sm.f.st[tid] += v;
            __syncthreads();
        }
        if (tid < 128) {
            int s0 = beg + sm.f.st[tid] - sm.f.lc[tid];
            slotstart[(b << 7) + tid] = s0;
            sm.f.lc[tid] = s0;
        }
        if (b == NBUCK - 1 && tid == 0) slotstart[MAX_SLOTS] = sm.f.tb[NBUCK - 1];
        __syncthreads();
        for (int j = beg + tid; j < end; j += TPB) {
            int e = bins[j];
            int pos = atomicAdd(&sm.f.lc[(e >> 17) & 127], 1);
            bins2[pos] = e & 0x1FFFF;
        }
    }
    gbar(cnt, 5 * GRID);

    // ---- Phase G: gather (wave per slot, grid-stride; uint4 = 8 rows/instr) ----
    {
        int nS = counters[0];
        int wv = blockIdx.x * (TPB / 64) + (tid >> 6);
        int lane = tid & 63;
        int rg = lane >> 3, dp = lane & 7;
        for (int s = wv; s < nS; s += GRID * (TPB / 64)) {
            int beg = slotstart[s], end = slotstart[s + 1];
            float a0 = 0.f, a1 = 0.f, a2 = 0.f, a3 = 0.f,
                  a4 = 0.f, a5 = 0.f, a6 = 0.f, a7 = 0.f;
            int j = beg;
            for (; j + 16 <= end; j += 16) {
                int e0 = bins2[j + rg];
                int e1 = bins2[j + 8 + rg];
                uint4 oa = wh4[(e0 << 3) + dp];
                uint4 ob = wh4[(e1 << 3) + dp];
                a0 += bfx(oa.x) + bfx(ob.x);
                a1 += bfx(oa.x >> 16) + bfx(ob.x >> 16);
                a2 += bfx(oa.y) + bfx(ob.y);
                a3 += bfx(oa.y >> 16) + bfx(ob.y >> 16);
                a4 += bfx(oa.z) + bfx(ob.z);
                a5 += bfx(oa.z >> 16) + bfx(ob.z >> 16);
                a6 += bfx(oa.w) + bfx(ob.w);
                a7 += bfx(oa.w >> 16) + bfx(ob.w >> 16);
            }
            for (; j < end; j += 8) {
                if (rg < end - j) {
                    int e0 = bins2[j + rg];
                    uint4 oa = wh4[(e0 << 3) + dp];
                    a0 += bfx(oa.x); a1 += bfx(oa.x >> 16);
                    a2 += bfx(oa.y); a3 += bfx(oa.y >> 16);
                    a4 += bfx(oa.z); a5 += bfx(oa.z >> 16);
                    a6 += bfx(oa.w); a7 += bfx(oa.w >> 16);
                }
            }
#pragma unroll
            for (int m = 8; m <= 32; m <<= 1) {
                a0 += __shfl_xor(a0, m, 64); a1 += __shfl_xor(a1, m, 64);
                a2 += __shfl_xor(a2, m, 64); a3 += __shfl_xor(a3, m, 64);
                a4 += __shfl_xor(a4, m, 64); a5 += __shfl_xor(a5, m, 64);
                a6 += __shfl_xor(a6, m, 64); a7 += __shfl_xor(a7, m, 64);
            }
            if (rg == 0) {
                int n = nodelist[s];
                float dn = dinv[n];
                uint4 u = wh4[(n << 3) + dp];
                float4 b0 = bias4[dp * 2], b1 = bias4[dp * 2 + 1];
                float r0 = (a0 + bfx(u.x)) * dn + b0.x;
                float r1 = (a1 + bfx(u.x >> 16)) * dn + b0.y;
                float r2 = (a2 + bfx(u.y)) * dn + b0.z;
                float r3 = (a3 + bfx(u.y >> 16)) * dn + b0.w;
                float r4 = (a4 + bfx(u.z)) * dn + b1.x;
                float r5 = (a5 + bfx(u.z >> 16)) * dn + b1.y;
                float r6 = (a6 + bfx(u.w)) * dn + b1.z;
                float r7 = (a7 + bfx(u.w >> 16)) * dn + b1.w;
                uint4 o;
                o.x = bfr(r0) | (bfr(r1) << 16);
                o.y = bfr(r2) | (bfr(r3) << 16);
                o.z = bfr(r4) | (bfr(r5) << 16);
                o.w = bfr(r6) | (bfr(r7) << 16);
                emb4[(s << 3) + dp] = o;
            }
        }
    }
    gbar(cnt, 6 * GRID);

    // ---- Phase H: FM dot + linear (4 pairs per wave, 16 lanes each) ----
    {
        int p = (blockIdx.x * TPB + tid) >> 4;
        int li = tid & 15;
        if (p < BATCH) {
            int a = pairs[p * 2], b = pairs[p * 2 + 1];
            int sa = (int)slot[a] - 1;
            int sb = (int)slot[b] - 1;
            uint2 ua = emb2[(sa << 4) + li];
            uint2 ub = emb2[(sb << 4) + li];
            float prod = bfx(ua.x) * bfx(ub.x) + bfx(ua.x >> 16) * bfx(ub.x >> 16)
                       + bfx(ua.y) * bfx(ub.y) + bfx(ua.y >> 16) * bfx(ub.y >> 16);
#pragma unroll
            for (int m = 1; m <= 8; m <<= 1) prod += __shfl_xor(prod, m, 64);
            if (li == 0) out[p] = lw[a] + lw[b] + lb[0] + prod;
        }
    }
}

extern "C" void kernel_launch(void* const* d_in, const int* in_sizes, int n_in,
                              void* d_out, int out_size, void* d_ws, size_t ws_size,
                              hipStream_t stream) {
    const float* gcn_weight    = (const float*)d_in[0];
    const float* gcn_bias      = (const float*)d_in[1];
    const float* linear_weight = (const float*)d_in[2];
    const float* linear_bias   = (const float*)d_in[3];
    const int*   edge_index    = (const int*)d_in[4];
    const int*   pairs         = (const int*)d_in[5];
    float* out = (float*)d_out;

    char* ws = (char*)d_ws;
    unsigned* slot     = (unsigned*)(ws + OFF_SLOT);
    int*      counters = (int*)     (ws + OFF_COUNTERS);

    const int* src_arr = edge_index;
    const int* dst_arr = edge_index + N_EDGES;

    k_init0<<<128, 256, 0, stream>>>(pairs, slot, counters);
    k_mega<<<GRID, TPB, 0, stream>>>((const float4*)gcn_weight, (const float4*)gcn_bias,
                                     linear_weight, linear_bias, src_arr, dst_arr,
                                     pairs, out, ws);
}

// Round 13
// 469.984 us; speedup vs baseline: 1.6632x; 1.6632x over previous
//
#include <hip/hip_runtime.h>

#define N_NODES 100000
#define N_EDGES 3200000
#define BATCH 16384
#define MAX_SLOTS 32768
#define MAGIC 0x5A5A5A5Au

#define GRID 512
#define TPB 512

// Degree histogram: nibble-packed, all 100K nodes in 50 KB LDS, 256 slices x 12500 edges.
#define NW 12500        // nibble words (8 nodes/word)
#define HSLICES 256
// Scatter: 512 sub-slices x 6250 edges (int2-aligned).
#define NSUB 512
#define NBUCK 256
#define BSH 7

// Workspace layout (byte offsets). ws_size = 256 MiB.
#define OFF_SLOT      0          // 100000 u32
#define OFF_COUNTERS  400000     // 16 ints: [0]=nSlots, [1]=grid barrier counter
#define OFF_DINV      400064     // 100000 f32
#define OFF_NODELIST  800064     // 32768 ints
#define OFF_BTOT      931136     // 256 ints
#define OFF_BPART     932160     // 256 x 512 ints [bucket][subslice]
#define OFF_SLOTSTART 1456448    // 32769 ints
#define OFF_PARTIALS  1587584    // 256 x 12500 words = 12.8 MB nibble degree counts
#define OFF_WH        14387584   // bf16 w*dinv, 100000x64x2 B
#define OFF_BINS      27187584   // packed (slot_local<<17|src), cap 1.2M
#define OFF_BINS2     31987584   // slot-sorted src ids, cap 1.2M
#define OFF_EMB       36787584   // bf16 32768x64

__device__ __forceinline__ unsigned bfr(float f) {   // fp32 -> bf16 bits, RNE
    unsigned u = __float_as_uint(f);
    return (u + 0x7FFFu + ((u >> 16) & 1u)) >> 16;
}
__device__ __forceinline__ float bfx(unsigned h) {   // low 16 bits -> fp32
    return __uint_as_float(h << 16);
}

// Software grid barrier, 3rd iteration.
//  r11: poll = atomicAdd(cnt,0) RMW  -> ownership serialization, ~65 us/barrier.
//  r12: poll = ACQUIRE load          -> buffer_inv per poll, device-wide cache
//       thrash, even slower (hbm 356->211 GB/s during work phases).
//  Fix: RELAXED polls (plain coherence-point read, no ownership, no invalidate),
//       then ONE acquire once target observed. Arrival = one RELEASE fetch_add.
__device__ __forceinline__ void gbar(int* cnt, int target) {
    __syncthreads();
    if (threadIdx.x == 0) {
        __hip_atomic_fetch_add(cnt, 1, __ATOMIC_RELEASE, __HIP_MEMORY_SCOPE_AGENT);
        while (__hip_atomic_load(cnt, __ATOMIC_RELAXED, __HIP_MEMORY_SCOPE_AGENT) < target)
            __builtin_amdgcn_s_sleep(16);
        (void)__hip_atomic_load(cnt, __ATOMIC_ACQUIRE, __HIP_MEMORY_SCOPE_AGENT);
    }
    __syncthreads();
}

// Launch 1: zero counters (incl. barrier counter) + mark needed nodes with MAGIC.
__global__ void k_init0(const int* __restrict__ pairs, unsigned* __restrict__ slot,
                        int* __restrict__ counters) {
    int i = blockIdx.x * blockDim.x + threadIdx.x;
    if (i < 16) counters[i] = 0;
    if (i < 2 * BATCH) slot[pairs[i]] = MAGIC;
}

__global__ __launch_bounds__(TPB, 4) void k_mega(
        const float4* __restrict__ w4, const float4* __restrict__ bias4,
        const float* __restrict__ lw, const float* __restrict__ lb,
        const int* __restrict__ src, const int* __restrict__ dst,
        const int* __restrict__ pairs, float* __restrict__ out, char* __restrict__ ws) {
    unsigned* slot      = (unsigned*)(ws + OFF_SLOT);
    int*      counters  = (int*)     (ws + OFF_COUNTERS);
    float*    dinv      = (float*)   (ws + OFF_DINV);
    int*      nodelist  = (int*)     (ws + OFF_NODELIST);
    int*      btot      = (int*)     (ws + OFF_BTOT);
    int*      bpart     = (int*)     (ws + OFF_BPART);
    int*      slotstart = (int*)     (ws + OFF_SLOTSTART);
    unsigned* partials  = (unsigned*)(ws + OFF_PARTIALS);
    uint4*    wh4       = (uint4*)   (ws + OFF_WH);
    int*      bins      = (int*)     (ws + OFF_BINS);
    int*      bins2     = (int*)     (ws + OFF_BINS2);
    uint4*    emb4      = (uint4*)   (ws + OFF_EMB);
    const uint2* emb2   = (const uint2*)(ws + OFF_EMB);
    int* cnt = &counters[1];

    __shared__ union SM {
        struct { unsigned h[NW]; int lc[2][NBUCK]; } c;                 // 52048 B max
        struct { unsigned p[4][TPB]; float sdinv[256]; } d;
        struct { int t[NSUB]; } pfx;
        struct { int tb[NBUCK], vv[NBUCK], cur[NBUCK]; } e;
        struct { int tb[NBUCK], vv[NBUCK], lc[128], st[128]; } f;
    } sm;

    int tid = threadIdx.x;

    // ---- Phase B: wave-aggregated compaction (writes every slot) ----
    {
        int n = blockIdx.x * TPB + tid;
        int lane = tid & 63;
        int want = (n < N_NODES && slot[n] == MAGIC) ? 1 : 0;
        int incl = want;
#pragma unroll
        for (int d = 1; d < 64; d <<= 1) {
            int t = __shfl_up(incl, d, 64);
            if (lane >= d) incl += t;
        }
        int total = __shfl(incl, 63, 64);
        int base = 0;
        if (lane == 63 && total > 0) base = atomicAdd(&counters[0], total);
        base = __shfl(base, 63, 64);
        if (n < N_NODES) {
            if (want) {
                int s = base + incl - 1;
                slot[n] = (unsigned)(s + 1);
                nodelist[s] = n;
            } else {
                slot[n] = 0u;
            }
        }
    }
    gbar(cnt, GRID);

    // ---- Phase C: nibble degree hist (all nodes) + per-half-slice bucket counts ----
    if (blockIdx.x < HSLICES) {
        int g = blockIdx.x;
        for (int i = tid; i < NW; i += TPB) sm.c.h[i] = 0;
        if (tid < NBUCK) { sm.c.lc[0][tid] = 0; sm.c.lc[1][tid] = 0; }
        __syncthreads();
        const int4* d4 = (const int4*)(dst + g * 12500);
        for (int i = tid; i < 3125; i += TPB) {
            int4 v = d4[i];
            atomicAdd(&sm.c.h[v.x >> 3], 1u << ((v.x & 7) << 2));
            atomicAdd(&sm.c.h[v.y >> 3], 1u << ((v.y & 7) << 2));
            atomicAdd(&sm.c.h[v.z >> 3], 1u << ((v.z & 7) << 2));
            atomicAdd(&sm.c.h[v.w >> 3], 1u << ((v.w & 7) << 2));
            int s01 = (i * 4) >= 6250;
            int s23 = (i * 4 + 2) >= 6250;
            unsigned r;
            r = slot[v.x]; if (r) atomicAdd(&sm.c.lc[s01][(r - 1) >> BSH], 1);
            r = slot[v.y]; if (r) atomicAdd(&sm.c.lc[s01][(r - 1) >> BSH], 1);
            r = slot[v.z]; if (r) atomicAdd(&sm.c.lc[s23][(r - 1) >> BSH], 1);
            r = slot[v.w]; if (r) atomicAdd(&sm.c.lc[s23][(r - 1) >> BSH], 1);
        }
        __syncthreads();
        unsigned* outp = partials + (unsigned)g * NW;
        for (int i = tid; i < NW; i += TPB) outp[i] = sm.c.h[i];
        if (tid < NBUCK) {
            bpart[tid * NSUB + g * 2]     = sm.c.lc[0][tid];
            bpart[tid * NSUB + g * 2 + 1] = sm.c.lc[1][tid];
        }
    }
    gbar(cnt, 2 * GRID);

    // ---- Phase D: blocks <391: partials -> dinv + bf16 wh; blocks >=391: bucket row scans ----
    if (blockIdx.x < 391) {
        int wi = tid & 31, sg = tid >> 5;             // word-in-block, slice-group (16 groups x 16)
        int w = blockIdx.x * 32 + wi;
        unsigned A = 0, Bu = 0, Cu = 0, Du = 0;
        if (w < NW) {
            const unsigned* q = partials + w;
            unsigned x = 0, y = 0;
#pragma unroll
            for (int k = 0; k < 16; ++k) {
                unsigned v = q[(unsigned)(sg * 16 + k) * NW];
                x += v & 0x0F0F0F0Fu;
                y += (v >> 4) & 0x0F0F0F0Fu;
            }
            A = x & 0x00FF00FFu; Bu = (x >> 8) & 0x00FF00FFu;
            Cu = y & 0x00FF00FFu; Du = (y >> 8) & 0x00FF00FFu;
        }
        sm.d.p[0][tid] = A; sm.d.p[1][tid] = Bu; sm.d.p[2][tid] = Cu; sm.d.p[3][tid] = Du;
        __syncthreads();
        if (tid < 32 && w < NW) {
            unsigned sA = 0, sB = 0, sC = 0, sD = 0;
#pragma unroll
            for (int k = 0; k < 16; ++k) {
                sA += sm.d.p[0][k * 32 + tid]; sB += sm.d.p[1][k * 32 + tid];
                sC += sm.d.p[2][k * 32 + tid]; sD += sm.d.p[3][k * 32 + tid];
            }
            float4 d0, d1;
            d0.x = rsqrtf((float)(sA & 0xFFFFu) + 1.0f);
            d0.y = rsqrtf((float)(sC & 0xFFFFu) + 1.0f);
            d0.z = rsqrtf((float)(sB & 0xFFFFu) + 1.0f);
            d0.w = rsqrtf((float)(sD & 0xFFFFu) + 1.0f);
            d1.x = rsqrtf((float)(sA >> 16) + 1.0f);
            d1.y = rsqrtf((float)(sC >> 16) + 1.0f);
            d1.z = rsqrtf((float)(sB >> 16) + 1.0f);
            d1.w = rsqrtf((float)(sD >> 16) + 1.0f);
            ((float4*)dinv)[w * 2] = d0;
            ((float4*)dinv)[w * 2 + 1] = d1;
            int lbm = tid * 8;
            sm.d.sdinv[lbm + 0] = d0.x; sm.d.sdinv[lbm + 1] = d0.y;
            sm.d.sdinv[lbm + 2] = d0.z; sm.d.sdinv[lbm + 3] = d0.w;
            sm.d.sdinv[lbm + 4] = d1.x; sm.d.sdinv[lbm + 5] = d1.y;
            sm.d.sdinv[lbm + 6] = d1.z; sm.d.sdinv[lbm + 7] = d1.w;
        }
        __syncthreads();
#pragma unroll
        for (int it = 0; it < 4; ++it) {
            int k = blockIdx.x * 2048 + it * TPB + tid;   // uint4 idx (8 dims); node = k>>3
            if (k < N_NODES * 8) {
                float4 va = w4[k * 2];
                float4 vb = w4[k * 2 + 1];
                float d = sm.d.sdinv[(k >> 3) - blockIdx.x * 256];
                uint4 o;
                o.x = bfr(va.x * d) | (bfr(va.y * d) << 16);
                o.y = bfr(va.z * d) | (bfr(va.w * d) << 16);
                o.z = bfr(vb.x * d) | (bfr(vb.y * d) << 16);
                o.w = bfr(vb.z * d) | (bfr(vb.w * d) << 16);
                wh4[k] = o;
            }
        }
    } else {
        for (int r = blockIdx.x - 391; r < NBUCK; r += 121) {
            int v = bpart[r * NSUB + tid];
            sm.pfx.t[tid] = v;
            __syncthreads();
            for (int off = 1; off < NSUB; off <<= 1) {
                int x = (tid >= off) ? sm.pfx.t[tid - off] : 0;
                __syncthreads();
                sm.pfx.t[tid] += x;
                __syncthreads();
            }
            bpart[r * NSUB + tid] = sm.pfx.t[tid] - v;
            if (tid == NSUB - 1) btot[r] = sm.pfx.t[tid];
            __syncthreads();
        }
    }
    gbar(cnt, 3 * GRID);

    // ---- Phase E: deterministic scatter (512 sub-slices of 6250 edges, int2) ----
    {
        int u = blockIdx.x;
        if (tid < NBUCK) { int v = btot[tid]; sm.e.vv[tid] = v; sm.e.tb[tid] = v; }
        __syncthreads();
        for (int off = 1; off < NBUCK; off <<= 1) {
            int x = (tid < NBUCK && tid >= off) ? sm.e.tb[tid - off] : 0;
            __syncthreads();
            if (tid < NBUCK) sm.e.tb[tid] += x;
            __syncthreads();
        }
        if (tid < NBUCK) sm.e.cur[tid] = sm.e.tb[tid] - sm.e.vv[tid] + bpart[tid * NSUB + u];
        __syncthreads();
        const int2* d2 = (const int2*)(dst + u * 6250);
        const int2* s2 = (const int2*)(src + u * 6250);
        for (int i = tid; i < 3125; i += TPB) {
            int2 d = d2[i];
            int2 s = s2[i];
            unsigned r;
            r = slot[d.x];
            if (r) {
                int sl = (int)r - 1;
                int pos = atomicAdd(&sm.e.cur[sl >> BSH], 1);
                bins[pos] = ((sl & 127) << 17) | s.x;
            }
            r = slot[d.y];
            if (r) {
                int sl = (int)r - 1;
                int pos = atomicAdd(&sm.e.cur[sl >> BSH], 1);
                bins[pos] = ((sl & 127) << 17) | s.y;
            }
        }
    }
    gbar(cnt, 4 * GRID);

    // ---- Phase F: per-bucket counting sort -> per-slot CSR ----
    if (blockIdx.x < NBUCK) {
        int b = blockIdx.x;
        if (tid < NBUCK) { int v = btot[tid]; sm.f.vv[tid] = v; sm.f.tb[tid] = v; }
        __syncthreads();
        for (int off = 1; off < NBUCK; off <<= 1) {
            int x = (tid < NBUCK && tid >= off) ? sm.f.tb[tid - off] : 0;
            __syncthreads();
            if (tid < NBUCK) sm.f.tb[tid] += x;
            __syncthreads();
        }
        int beg = sm.f.tb[b] - sm.f.vv[b];
        int end = beg + sm.f.vv[b];
        if (tid < 128) sm.f.lc[tid] = 0;
        __syncthreads();
        for (int j = beg + tid; j < end; j += TPB)
            atomicAdd(&sm.f.lc[(bins[j] >> 17) & 127], 1);
        __syncthreads();
        if (tid < 128) sm.f.st[tid] = sm.f.lc[tid];
        __syncthreads();
        for (int off = 1; off < 128; off <<= 1) {
            int v = (tid < 128 && tid >= off) ? sm.f.st[tid - off] : 0;
            __syncthreads();
            if (tid < 128) sm.f.st[tid] += v;
            __syncthreads();
        }
        if (tid < 128) {
            int s0 = beg + sm.f.st[tid] - sm.f.lc[tid];
            slotstart[(b << 7) + tid] = s0;
            sm.f.lc[tid] = s0;
        }
        if (b == NBUCK - 1 && tid == 0) slotstart[MAX_SLOTS] = sm.f.tb[NBUCK - 1];
        __syncthreads();
        for (int j = beg + tid; j < end; j += TPB) {
            int e = bins[j];
            int pos = atomicAdd(&sm.f.lc[(e >> 17) & 127], 1);
            bins2[pos] = e & 0x1FFFF;
        }
    }
    gbar(cnt, 5 * GRID);

    // ---- Phase G: gather (wave per slot, grid-stride; uint4 = 8 rows/instr) ----
    {
        int nS = counters[0];
        int wv = blockIdx.x * (TPB / 64) + (tid >> 6);
        int lane = tid & 63;
        int rg = lane >> 3, dp = lane & 7;
        for (int s = wv; s < nS; s += GRID * (TPB / 64)) {
            int beg = slotstart[s], end = slotstart[s + 1];
            float a0 = 0.f, a1 = 0.f, a2 = 0.f, a3 = 0.f,
                  a4 = 0.f, a5 = 0.f, a6 = 0.f, a7 = 0.f;
            int j = beg;
            for (; j + 16 <= end; j += 16) {
                int e0 = bins2[j + rg];
                int e1 = bins2[j + 8 + rg];
                uint4 oa = wh4[(e0 << 3) + dp];
                uint4 ob = wh4[(e1 << 3) + dp];
                a0 += bfx(oa.x) + bfx(ob.x);
                a1 += bfx(oa.x >> 16) + bfx(ob.x >> 16);
                a2 += bfx(oa.y) + bfx(ob.y);
                a3 += bfx(oa.y >> 16) + bfx(ob.y >> 16);
                a4 += bfx(oa.z) + bfx(ob.z);
                a5 += bfx(oa.z >> 16) + bfx(ob.z >> 16);
                a6 += bfx(oa.w) + bfx(ob.w);
                a7 += bfx(oa.w >> 16) + bfx(ob.w >> 16);
            }
            for (; j < end; j += 8) {
                if (rg < end - j) {
                    int e0 = bins2[j + rg];
                    uint4 oa = wh4[(e0 << 3) + dp];
                    a0 += bfx(oa.x); a1 += bfx(oa.x >> 16);
                    a2 += bfx(oa.y); a3 += bfx(oa.y >> 16);
                    a4 += bfx(oa.z); a5 += bfx(oa.z >> 16);
                    a6 += bfx(oa.w); a7 += bfx(oa.w >> 16);
                }
            }
#pragma unroll
            for (int m = 8; m <= 32; m <<= 1) {
                a0 += __shfl_xor(a0, m, 64); a1 += __shfl_xor(a1, m, 64);
                a2 += __shfl_xor(a2, m, 64); a3 += __shfl_xor(a3, m, 64);
                a4 += __shfl_xor(a4, m, 64); a5 += __shfl_xor(a5, m, 64);
                a6 += __shfl_xor(a6, m, 64); a7 += __shfl_xor(a7, m, 64);
            }
            if (rg == 0) {
                int n = nodelist[s];
                float dn = dinv[n];
                uint4 u = wh4[(n << 3) + dp];
                float4 b0 = bias4[dp * 2], b1 = bias4[dp * 2 + 1];
                float r0 = (a0 + bfx(u.x)) * dn + b0.x;
                float r1 = (a1 + bfx(u.x >> 16)) * dn + b0.y;
                float r2 = (a2 + bfx(u.y)) * dn + b0.z;
                float r3 = (a3 + bfx(u.y >> 16)) * dn + b0.w;
                float r4 = (a4 + bfx(u.z)) * dn + b1.x;
                float r5 = (a5 + bfx(u.z >> 16)) * dn + b1.y;
                float r6 = (a6 + bfx(u.w)) * dn + b1.z;
                float r7 = (a7 + bfx(u.w >> 16)) * dn + b1.w;
                uint4 o;
                o.x = bfr(r0) | (bfr(r1) << 16);
                o.y = bfr(r2) | (bfr(r3) << 16);
                o.z = bfr(r4) | (bfr(r5) << 16);
                o.w = bfr(r6) | (bfr(r7) << 16);
                emb4[(s << 3) + dp] = o;
            }
        }
    }
    gbar(cnt, 6 * GRID);

    // ---- Phase H: FM dot + linear (4 pairs per wave, 16 lanes each) ----
    {
        int p = (blockIdx.x * TPB + tid) >> 4;
        int li = tid & 15;
        if (p < BATCH) {
            int a = pairs[p * 2], b = pairs[p * 2 + 1];
            int sa = (int)slot[a] - 1;
            int sb = (int)slot[b] - 1;
            uint2 ua = emb2[(sa << 4) + li];
            uint2 ub = emb2[(sb << 4) + li];
            float prod = bfx(ua.x) * bfx(ub.x) + bfx(ua.x >> 16) * bfx(ub.x >> 16)
                       + bfx(ua.y) * bfx(ub.y) + bfx(ua.y >> 16) * bfx(ub.y >> 16);
#pragma unroll
            for (int m = 1; m <= 8; m <<= 1) prod += __shfl_xor(prod, m, 64);
            if (li == 0) out[p] = lw[a] + lw[b] + lb[0] + prod;
        }
    }
}

extern "C" void kernel_launch(void* const* d_in, const int* in_sizes, int n_in,
                              void* d_out, int out_size, void* d_ws, size_t ws_size,
                              hipStream_t stream) {
    const float* gcn_weight    = (const float*)d_in[0];
    const float* gcn_bias      = (const float*)d_in[1];
    const float* linear_weight = (const float*)d_in[2];
    const float* linear_bias   = (const float*)d_in[3];
    const int*   edge_index    = (const int*)d_in[4];
    const int*   pairs         = (const int*)d_in[5];
    float* out = (float*)d_out;

    char* ws = (char*)d_ws;
    unsigned* slot     = (unsigned*)(ws + OFF_SLOT);
    int*      counters = (int*)     (ws + OFF_COUNTERS);

    const int* src_arr = edge_index;
    const int* dst_arr = edge_index + N_EDGES;

    k_init0<<<128, 256, 0, stream>>>(pairs, slot, counters);
    k_mega<<<GRID, TPB, 0, stream>>>((const float4*)gcn_weight, (const float4*)gcn_bias,
                                     linear_weight, linear_bias, src_arr, dst_arr,
                                     pairs, out, ws);
}

// Round 14
// 191.720 us; speedup vs baseline: 4.0771x; 2.4514x over previous
//
#include <hip/hip_runtime.h>

#define N_NODES 100000
#define N_EDGES 3200000
#define BATCH 16384
#define MAX_SLOTS 32768

// Single-pass nibble-packed degree histogram: 100K nodes x 4 bit = 50 KB LDS.
#define NW 12500       // words (8 nodes/word)
#define SLICES 256
#define EPS2 12500     // edges per slice
#define I4PS2 3125

// Bucket machinery over slot space (128 slots / bucket).
#define NBUCK 256
#define BSH 7

// Workspace layout (byte offsets). ws_size = 256 MiB.
#define OFF_SLOT      0          // 100000 u32 (i+1 for needed winners; garbage elsewhere)
#define OFF_DINV      400064     // 100000 f32 (16B aligned)
#define OFF_NODELIST  800064     // 32768 ints (slot -> node, with duplicates)
#define OFF_BTOT      931136     // 256 ints
#define OFF_BPART     932160     // 256x256 ints [bucket][slice]
#define OFF_SLOTSTART 1194304    // 32769 ints
#define OFF_PARTIALS  1325440    // 256 x 12500 words = 12.8 MB nibble degree counts
#define OFF_WH        14125440   // bf16 w*dinv, 100000x64x2 B (16B aligned)
#define OFF_BINS      26925440   // packed (slot_local<<17|src), cap 1.2M
#define OFF_BINS2     31725440   // slot-sorted src ids, cap 1.2M
#define OFF_EMB       36525440   // bf16 32768x64

__device__ __forceinline__ unsigned bfr(float f) {   // fp32 -> bf16 bits, RNE
    unsigned u = __float_as_uint(f);
    return (u + 0x7FFFu + ((u >> 16) & 1u)) >> 16;
}
__device__ __forceinline__ float bfx(unsigned h) {   // low 16 bits -> fp32
    return __uint_as_float(h << 16);
}

// No-dedup slot assignment: slot[n] races to one winner; losers' slots get empty
// bins and their emb is computed-but-never-read. Self-certification (below) makes
// any pre-existing slot[] content safe -> no init pass, no compaction pass.
__global__ void k_flags(const int* __restrict__ pairs, unsigned* __restrict__ slot,
                        int* __restrict__ nodelist) {
    int i = blockIdx.x * blockDim.x + threadIdx.x;
    if (i < 2 * BATCH) {
        int n = pairs[i];
        nodelist[i] = n;
        slot[n] = (unsigned)(i + 1);
    }
}

// Certified needed-test: r=slot[d] valid iff (r-1)<32768 AND nodelist[r-1]==d.
// Garbage slot values for unneeded nodes cannot certify (nodelist holds only
// needed nodes, d is unneeded -> mismatch).
__device__ __forceinline__ int cert(int d, const unsigned* __restrict__ slot,
                                    const int* __restrict__ nodelist) {
    unsigned r = slot[d];
    unsigned idx = r - 1u;
    if (idx < (unsigned)MAX_SLOTS && nodelist[idx] == d) return (int)idx;
    return -1;
}

// FUSED single-pass: nibble-packed degree histogram (ALL nodes, 50 KB LDS) +
// per-bucket certified edge counting. dst read exactly once.
__global__ void k_hist(const int* __restrict__ dst, const unsigned* __restrict__ slot,
                       const int* __restrict__ nodelist,
                       unsigned* __restrict__ partials, int* __restrict__ bpart) {
    __shared__ unsigned h[NW];
    __shared__ int lc[NBUCK];
    int g = blockIdx.x;
    for (int i = threadIdx.x; i < NW; i += 512) h[i] = 0;
    if (threadIdx.x < NBUCK) lc[threadIdx.x] = 0;
    __syncthreads();
    const int4* d4 = (const int4*)(dst + g * EPS2);
    for (int i = threadIdx.x; i < I4PS2; i += 512) {
        int4 v = d4[i];
        atomicAdd(&h[v.x >> 3], 1u << ((v.x & 7) << 2));
        atomicAdd(&h[v.y >> 3], 1u << ((v.y & 7) << 2));
        atomicAdd(&h[v.z >> 3], 1u << ((v.z & 7) << 2));
        atomicAdd(&h[v.w >> 3], 1u << ((v.w & 7) << 2));
        int t;
        t = cert(v.x, slot, nodelist); if (t >= 0) atomicAdd(&lc[t >> BSH], 1);
        t = cert(v.y, slot, nodelist); if (t >= 0) atomicAdd(&lc[t >> BSH], 1);
        t = cert(v.z, slot, nodelist); if (t >= 0) atomicAdd(&lc[t >> BSH], 1);
        t = cert(v.w, slot, nodelist); if (t >= 0) atomicAdd(&lc[t >> BSH], 1);
    }
    __syncthreads();
    unsigned* outp = partials + (unsigned)g * NW;
    for (int i = threadIdx.x; i < NW; i += 512) outp[i] = h[i];
    if (threadIdx.x < NBUCK) bpart[threadIdx.x * SLICES + g] = lc[threadIdx.x];
}

// Combined dispatch: blocks [0,391) reduce nibble partials -> dinv and convert w
// rows to bf16 wh = w*dinv; blocks [391, 391+256) do the per-bucket slice scan.
__global__ void k_mid(const unsigned* __restrict__ partials, const float4* __restrict__ w4,
                      float* __restrict__ dinv, uint4* __restrict__ wh4,
                      int* __restrict__ bpart, int* __restrict__ btot) {
    if (blockIdx.x >= 391) {
        __shared__ int t[SLICES];
        int b = blockIdx.x - 391, g = threadIdx.x;
        int v = bpart[b * SLICES + g];
        t[g] = v;
        __syncthreads();
        for (int off = 1; off < SLICES; off <<= 1) {
            int x = (g >= off) ? t[g - off] : 0;
            __syncthreads();
            t[g] += x;
            __syncthreads();
        }
        bpart[b * SLICES + g] = t[g] - v;
        if (g == SLICES - 1) btot[b] = t[g];
        return;
    }
    __shared__ unsigned pA[256], pB[256], pC[256], pD[256];
    __shared__ float sdinv[256];
    int blk = blockIdx.x;
    int wi = threadIdx.x & 31, sg = threadIdx.x >> 5;    // word-in-block, slice-group
    int w = blk * 32 + wi;
    unsigned A = 0, B = 0, C = 0, D = 0;
    if (w < NW) {
        const unsigned* q = partials + w;
#pragma unroll
        for (int ch = 0; ch < 2; ++ch) {                 // 2 chunks x 16 slices
            unsigned x = 0, y = 0;
#pragma unroll
            for (int k = 0; k < 16; ++k) {
                unsigned v = q[(unsigned)(sg * 32 + ch * 16 + k) * NW];
                x += v & 0x0F0F0F0Fu;
                y += (v >> 4) & 0x0F0F0F0Fu;
            }
            A += x & 0x00FF00FFu;          // (n0, n4)
            B += (x >> 8) & 0x00FF00FFu;   // (n2, n6)
            C += y & 0x00FF00FFu;          // (n1, n5)
            D += (y >> 8) & 0x00FF00FFu;   // (n3, n7)
        }
    }
    pA[threadIdx.x] = A; pB[threadIdx.x] = B; pC[threadIdx.x] = C; pD[threadIdx.x] = D;
    __syncthreads();
    if (threadIdx.x < 32 && w < NW) {
        unsigned sA = 0, sB = 0, sC = 0, sD = 0;
#pragma unroll
        for (int k = 0; k < 8; ++k) {
            sA += pA[k * 32 + wi]; sB += pB[k * 32 + wi];
            sC += pC[k * 32 + wi]; sD += pD[k * 32 + wi];
        }
        float4 d0, d1;
        d0.x = rsqrtf((float)(sA & 0xFFFFu) + 1.0f);
        d0.y = rsqrtf((float)(sC & 0xFFFFu) + 1.0f);
        d0.z = rsqrtf((float)(sB & 0xFFFFu) + 1.0f);
        d0.w = rsqrtf((float)(sD & 0xFFFFu) + 1.0f);
        d1.x = rsqrtf((float)(sA >> 16) + 1.0f);
        d1.y = rsqrtf((float)(sC >> 16) + 1.0f);
        d1.z = rsqrtf((float)(sB >> 16) + 1.0f);
        d1.w = rsqrtf((float)(sD >> 16) + 1.0f);
        ((float4*)dinv)[w * 2] = d0;
        ((float4*)dinv)[w * 2 + 1] = d1;
        int lb = wi * 8;
        sdinv[lb + 0] = d0.x; sdinv[lb + 1] = d0.y; sdinv[lb + 2] = d0.z; sdinv[lb + 3] = d0.w;
        sdinv[lb + 4] = d1.x; sdinv[lb + 5] = d1.y; sdinv[lb + 6] = d1.z; sdinv[lb + 7] = d1.w;
    }
    __syncthreads();
#pragma unroll
    for (int it = 0; it < 8; ++it) {
        int k = blk * 2048 + it * 256 + threadIdx.x;   // uint4 index (8 dims); node = k>>3
        if (k < N_NODES * 8) {
            float4 va = w4[k * 2];
            float4 vb = w4[k * 2 + 1];
            float d = sdinv[(k >> 3) - blk * 256];
            uint4 o;
            o.x = bfr(va.x * d) | (bfr(va.y * d) << 16);
            o.y = bfr(va.z * d) | (bfr(va.w * d) << 16);
            o.z = bfr(vb.x * d) | (bfr(vb.y * d) << 16);
            o.w = bfr(vb.z * d) | (bfr(vb.w * d) << 16);
            wh4[k] = o;
        }
    }
}

// Deterministic scatter; each block recomputes the 256-bucket scan from btot.
__global__ void k_bscatter(const int* __restrict__ src, const int* __restrict__ dst,
                           const unsigned* __restrict__ slot, const int* __restrict__ nodelist,
                           const int* __restrict__ bpart, const int* __restrict__ btot,
                           int* __restrict__ bins) {
    __shared__ int tb[NBUCK], vv[NBUCK], cur[NBUCK];
    int g = blockIdx.x;
    int t = threadIdx.x;
    if (t < NBUCK) { int v = btot[t]; vv[t] = v; tb[t] = v; }
    __syncthreads();
    for (int off = 1; off < NBUCK; off <<= 1) {
        int x = (t < NBUCK && t >= off) ? tb[t - off] : 0;
        __syncthreads();
        if (t < NBUCK) tb[t] += x;
        __syncthreads();
    }
    if (t < NBUCK) cur[t] = tb[t] - vv[t] + bpart[t * SLICES + g];
    __syncthreads();
    const int4* d4 = (const int4*)(dst + g * EPS2);
    const int4* s4 = (const int4*)(src + g * EPS2);
    for (int i = t; i < I4PS2; i += 512) {
        int4 d = d4[i];
        int4 s = s4[i];
        int sl;
        sl = cert(d.x, slot, nodelist);
        if (sl >= 0) { int pos = atomicAdd(&cur[sl >> BSH], 1); bins[pos] = ((sl & 127) << 17) | s.x; }
        sl = cert(d.y, slot, nodelist);
        if (sl >= 0) { int pos = atomicAdd(&cur[sl >> BSH], 1); bins[pos] = ((sl & 127) << 17) | s.y; }
        sl = cert(d.z, slot, nodelist);
        if (sl >= 0) { int pos = atomicAdd(&cur[sl >> BSH], 1); bins[pos] = ((sl & 127) << 17) | s.z; }
        sl = cert(d.w, slot, nodelist);
        if (sl >= 0) { int pos = atomicAdd(&cur[sl >> BSH], 1); bins[pos] = ((sl & 127) << 17) | s.w; }
    }
}

// Per-bucket counting sort -> per-slot CSR; bucket bounds from inline btot scan.
__global__ void k_bsort(const int* __restrict__ btot, const int* __restrict__ bins,
                        int* __restrict__ slotstart, int* __restrict__ bins2) {
    __shared__ int tb[NBUCK], vv[NBUCK];
    __shared__ int lc[128], st[128];
    int b = blockIdx.x;
    int tid = threadIdx.x;
    { int v = btot[tid]; vv[tid] = v; tb[tid] = v; }
    __syncthreads();
    for (int off = 1; off < NBUCK; off <<= 1) {
        int x = (tid >= off) ? tb[tid - off] : 0;
        __syncthreads();
        tb[tid] += x;
        __syncthreads();
    }
    int beg = tb[b] - vv[b];
    int end = beg + vv[b];
    if (tid < 128) lc[tid] = 0;
    __syncthreads();
    for (int j = beg + tid; j < end; j += 256)
        atomicAdd(&lc[(bins[j] >> 17) & 127], 1);
    __syncthreads();
    if (tid < 128) st[tid] = lc[tid];
    __syncthreads();
    for (int off = 1; off < 128; off <<= 1) {
        int v = (tid < 128 && tid >= off) ? st[tid - off] : 0;
        __syncthreads();
        if (tid < 128) st[tid] += v;
        __syncthreads();
    }
    if (tid < 128) {
        int s0 = beg + st[tid] - lc[tid];
        slotstart[(b << 7) + tid] = s0;
        lc[tid] = s0;
    }
    if (b == NBUCK - 1 && tid == 0) slotstart[MAX_SLOTS] = tb[NBUCK - 1];
    __syncthreads();
    for (int j = beg + tid; j < end; j += 256) {
        int e = bins[j];
        int pos = atomicAdd(&lc[(e >> 17) & 127], 1);
        bins2[pos] = e & 0x1FFFF;
    }
}

// One wave per slot (all 32768, empty loser slots are trivial), 8 rows per
// instruction: lane = (rg = lane>>3) x (dp = lane&7), uint4 loads.
__global__ void k_gather(const int* __restrict__ nodelist, const int* __restrict__ slotstart,
                         const int* __restrict__ bins2, const uint4* __restrict__ wh4,
                         const float* __restrict__ dinv, const float4* __restrict__ bias4,
                         uint4* __restrict__ emb4) {
    int s = (blockIdx.x * blockDim.x + threadIdx.x) >> 6;
    int lane = threadIdx.x & 63;
    int rg = lane >> 3, dp = lane & 7;
    int beg = slotstart[s], end = slotstart[s + 1];
    float a0 = 0.f, a1 = 0.f, a2 = 0.f, a3 = 0.f, a4 = 0.f, a5 = 0.f, a6 = 0.f, a7 = 0.f;
    int j = beg;
    for (; j + 16 <= end; j += 16) {
        int e0 = bins2[j + rg];
        int e1 = bins2[j + 8 + rg];
        uint4 oa = wh4[(e0 << 3) + dp];
        uint4 ob = wh4[(e1 << 3) + dp];
        a0 += bfx(oa.x) + bfx(ob.x);
        a1 += bfx(oa.x >> 16) + bfx(ob.x >> 16);
        a2 += bfx(oa.y) + bfx(ob.y);
        a3 += bfx(oa.y >> 16) + bfx(ob.y >> 16);
        a4 += bfx(oa.z) + bfx(ob.z);
        a5 += bfx(oa.z >> 16) + bfx(ob.z >> 16);
        a6 += bfx(oa.w) + bfx(ob.w);
        a7 += bfx(oa.w >> 16) + bfx(ob.w >> 16);
    }
    for (; j < end; j += 8) {
        if (rg < end - j) {
            int e0 = bins2[j + rg];
            uint4 oa = wh4[(e0 << 3) + dp];
            a0 += bfx(oa.x); a1 += bfx(oa.x >> 16);
            a2 += bfx(oa.y); a3 += bfx(oa.y >> 16);
            a4 += bfx(oa.z); a5 += bfx(oa.z >> 16);
            a6 += bfx(oa.w); a7 += bfx(oa.w >> 16);
        }
    }
#pragma unroll
    for (int m = 8; m <= 32; m <<= 1) {
        a0 += __shfl_xor(a0, m, 64); a1 += __shfl_xor(a1, m, 64);
        a2 += __shfl_xor(a2, m, 64); a3 += __shfl_xor(a3, m, 64);
        a4 += __shfl_xor(a4, m, 64); a5 += __shfl_xor(a5, m, 64);
        a6 += __shfl_xor(a6, m, 64); a7 += __shfl_xor(a7, m, 64);
    }
    if (rg == 0) {
        int n = nodelist[s];
        float dn = dinv[n];
        uint4 u = wh4[(n << 3) + dp];
        float4 b0 = bias4[dp * 2], b1 = bias4[dp * 2 + 1];
        float r0 = (a0 + bfx(u.x)) * dn + b0.x;
        float r1 = (a1 + bfx(u.x >> 16)) * dn + b0.y;
        float r2 = (a2 + bfx(u.y)) * dn + b0.z;
        float r3 = (a3 + bfx(u.y >> 16)) * dn + b0.w;
        float r4 = (a4 + bfx(u.z)) * dn + b1.x;
        float r5 = (a5 + bfx(u.z >> 16)) * dn + b1.y;
        float r6 = (a6 + bfx(u.w)) * dn + b1.z;
        float r7 = (a7 + bfx(u.w >> 16)) * dn + b1.w;
        uint4 o;
        o.x = bfr(r0) | (bfr(r1) << 16);
        o.y = bfr(r2) | (bfr(r3) << 16);
        o.z = bfr(r4) | (bfr(r5) << 16);
        o.w = bfr(r6) | (bfr(r7) << 16);
        emb4[(s << 3) + dp] = o;
    }
}

// Four pairs per wave (16 lanes each), uint2 loads (4 dims/lane). slot[a] is
// always a winner id for pair nodes.
__global__ void k_final(const int* __restrict__ pairs, const unsigned* __restrict__ slot,
                        const uint2* __restrict__ emb2, const float* __restrict__ lw,
                        const float* __restrict__ lb, float* __restrict__ out) {
    int p = (blockIdx.x * blockDim.x + threadIdx.x) >> 4;
    int li = threadIdx.x & 15;
    if (p >= BATCH) return;
    int a = pairs[p * 2], b = pairs[p * 2 + 1];
    int sa = (int)slot[a] - 1;
    int sb = (int)slot[b] - 1;
    uint2 ua = emb2[(sa << 4) + li];
    uint2 ub = emb2[(sb << 4) + li];
    float prod = bfx(ua.x) * bfx(ub.x) + bfx(ua.x >> 16) * bfx(ub.x >> 16)
               + bfx(ua.y) * bfx(ub.y) + bfx(ua.y >> 16) * bfx(ub.y >> 16);
#pragma unroll
    for (int m = 1; m <= 8; m <<= 1) prod += __shfl_xor(prod, m, 64);
    if (li == 0) out[p] = lw[a] + lw[b] + lb[0] + prod;
}

extern "C" void kernel_launch(void* const* d_in, const int* in_sizes, int n_in,
                              void* d_out, int out_size, void* d_ws, size_t ws_size,
                              hipStream_t stream) {
    const float* gcn_weight    = (const float*)d_in[0];
    const float* gcn_bias      = (const float*)d_in[1];
    const float* linear_weight = (const float*)d_in[2];
    const float* linear_bias   = (const float*)d_in[3];
    const int*   edge_index    = (const int*)d_in[4];
    const int*   pairs         = (const int*)d_in[5];
    float* out = (float*)d_out;

    char* ws = (char*)d_ws;
    unsigned* slot      = (unsigned*)(ws + OFF_SLOT);
    float*    dinv      = (float*)   (ws + OFF_DINV);
    int*      nodelist  = (int*)     (ws + OFF_NODELIST);
    int*      btot      = (int*)     (ws + OFF_BTOT);
    int*      bpart     = (int*)     (ws + OFF_BPART);
    int*      slotstart = (int*)     (ws + OFF_SLOTSTART);
    unsigned* partials  = (unsigned*)(ws + OFF_PARTIALS);
    uint4*    wh4       = (uint4*)   (ws + OFF_WH);
    int*      bins      = (int*)     (ws + OFF_BINS);
    int*      bins2     = (int*)     (ws + OFF_BINS2);
    uint4*    emb4      = (uint4*)   (ws + OFF_EMB);
    uint2*    emb2      = (uint2*)   (ws + OFF_EMB);

    const int* src_arr = edge_index;
    const int* dst_arr = edge_index + N_EDGES;

    k_flags<<<128, 256, 0, stream>>>(pairs, slot, nodelist);
    k_hist<<<SLICES, 512, 0, stream>>>(dst_arr, slot, nodelist, partials, bpart);
    k_mid<<<391 + 256, 256, 0, stream>>>(partials, (const float4*)gcn_weight, dinv, wh4,
                                         bpart, btot);
    k_bscatter<<<SLICES, 512, 0, stream>>>(src_arr, dst_arr, slot, nodelist, bpart, btot, bins);
    k_bsort<<<NBUCK, 256, 0, stream>>>(btot, bins, slotstart, bins2);
    k_gather<<<MAX_SLOTS / 4, 256, 0, stream>>>(nodelist, slotstart, bins2, wh4,
                                                dinv, (const float4*)gcn_bias, emb4);
    k_final<<<1024, 256, 0, stream>>>(pairs, slot, emb2, linear_weight, linear_bias, out);
}